// Round 5
// baseline (276.209 us; speedup 1.0000x reference)
//
#include <hip/hip_runtime.h>
#include <math.h>

// Problem constants: B=64, IN=1024, OUT=512, T=512, V_TH=1, TAU=16
#define BATCH   64
#define INS     1024
#define OUTS    512
#define TSTEPS  512
#define TAUF    16.0f

// ---------------------------------------------------------------------------
// Fused pre-kernel: blocks [0,128) tiled weight transpose w[OUT,IN]->wT[IN,OUT];
// blocks [128,192) per-batch spike prep + counting sort by activation time.
//   alpha(t-s) = e^{-t/tau} * (t*A + C) for t > s,
//   A = exp(1 + s/tau)/tau,  C = -s*A,  t_on = floor(s)+1 in [1,256].
// Record per spike (sorted by t_on):
//   {A, int_bits(idx*OUTS/2), C, int_bits(t_on)}  -- int bits avoid per-spike
//   v_cvt/v_mul in the scan kernel's inner loop.
// ---------------------------------------------------------------------------
#define TT 64
#define NTRANS ((INS / TT) * (OUTS / TT))   // 128 transpose blocks

__global__ __launch_bounds__(256) void pre_kernel(
        const float* __restrict__ w, float* __restrict__ wT,
        const float* __restrict__ in_spike, float4* __restrict__ spk) {
    __shared__ float tile[TT][TT + 1];
    __shared__ int hist[257];
    __shared__ int cursor[257];
    __shared__ int scanbuf[256];

    if (blockIdx.x < NTRANS) {
        const int i0 = (blockIdx.x & (INS / TT - 1)) * TT;
        const int o0 = (blockIdx.x / (INS / TT)) * TT;
        const int c  = threadIdx.x & 63;
        const int r  = threadIdx.x >> 6;
#pragma unroll
        for (int rr = r; rr < TT; rr += 4)
            tile[rr][c] = w[(o0 + rr) * INS + i0 + c];
        __syncthreads();
#pragma unroll
        for (int rr = r; rr < TT; rr += 4)
            wT[(i0 + rr) * OUTS + o0 + c] = tile[c][rr];
        return;
    }

    const int b = blockIdx.x - NTRANS;
    for (int k = threadIdx.x; k < 257; k += 256) hist[k] = 0;
    __syncthreads();

    float sv[INS / 256];
    int   tv[INS / 256];
#pragma unroll
    for (int j = 0; j < INS / 256; ++j) {
        int i = threadIdx.x + j * 256;
        float s = in_spike[b * INS + i];
        sv[j] = s;
        int t = (int)floorf(s) + 1;
        t = t < 1 ? 1 : (t > 256 ? 256 : t);
        tv[j] = t;
        atomicAdd(&hist[t], 1);
    }
    __syncthreads();

    const int tid = threadIdx.x;
    int v = hist[tid + 1];
    scanbuf[tid] = v;
    __syncthreads();
#pragma unroll
    for (int off = 1; off < 256; off <<= 1) {
        int add = (tid >= off) ? scanbuf[tid - off] : 0;
        __syncthreads();
        scanbuf[tid] += add;
        __syncthreads();
    }
    cursor[tid + 1] = scanbuf[tid] - v;
    __syncthreads();

#pragma unroll
    for (int j = 0; j < INS / 256; ++j) {
        int i = threadIdx.x + j * 256;
        int t = tv[j];
        int pos = atomicAdd(&cursor[t], 1);
        float A = expf(fmaf(sv[j], 1.0f / TAUF, 1.0f)) * (1.0f / TAUF);
        float C = -sv[j] * A;
        spk[b * INS + pos] =
            make_float4(A, __int_as_float(i * (OUTS / 2)), C, __int_as_float(t));
    }
}

// ---------------------------------------------------------------------------
// Scan kernel.  Block = (b, 64 outputs), 1024 threads: threadIdx.x = lane
// (32), each thread owns outputs (2x, 2x+1) via float2 gathers; threadIdx.y
// = time-sorted chunk g of 32 (32 spikes each).  Pass 1: chunk partials.
// LDS exclusive scan over g (also yields full totals).  Pass 2: re-walk own
// chunk with threshold checks over the owned time range; the spike-free tail
// [257,512) is split 8 steps per g-thread using the totals.  Ranges
// partition the time axis -> atomicMin over per-range first crossings is
// exact.  V(t)>=1 <=> fma(t,SA,SC) >= exp(t/tau).
// Grid = 64*8 = 512 blocks of 16 waves -> 2 blocks/CU = 32 waves/CU.
// Wave = 32 lanes x 2 g-chunks -> LDS addresses 2-way aliased only (free).
// ---------------------------------------------------------------------------
#define OL 32            // lanes (output pairs) per block
#define G  32            // chunks per output
#define CH (INS / G)     // 32 spikes per chunk
#define TAIL0 257        // first spike-free time step (t_on <= 256)

__global__ __launch_bounds__(OL * G, 8) void spike_scan_kernel(
        const float4* __restrict__ spk, const float* __restrict__ wT,
        float* __restrict__ out) {
    const int b = blockIdx.x;
    const int x = threadIdx.x;           // 0..31 lane
    const int g = threadIdx.y;           // 0..31 chunk
    const int tid = g * OL + x;

    __shared__ float4 sspk[INS];         // 16 KB
    __shared__ float  sE[TSTEPS];        // 2 KB: exp(t/tau)
    __shared__ float2 psA[G][OL];        // 8 KB (per-output pair partials)
    __shared__ float2 psC[G][OL];        // 8 KB
    __shared__ int    sFirst[2 * OL];    // 256 B

    const float4* bspk = spk + b * INS;
    sspk[tid] = bspk[tid];
    if (tid < TSTEPS) sE[tid] = expf((float)tid * (1.0f / TAUF));
    if (tid < 2 * OL) sFirst[tid] = TSTEPS;
    __syncthreads();

    const int k0 = g * CH;
    const float2* __restrict__ wT2 = (const float2*)wT;
    const int myo = blockIdx.y * OL + x;          // float2 column index

    // ---- pass 1: chunk partials for outputs (2x, 2x+1) ----
    float pA0 = 0.f, pC0 = 0.f, pA1 = 0.f, pC1 = 0.f;
#pragma unroll
    for (int kk = 0; kk < CH; kk += 4) {
        float4 p0 = sspk[k0 + kk + 0];
        float4 p1 = sspk[k0 + kk + 1];
        float4 p2 = sspk[k0 + kk + 2];
        float4 p3 = sspk[k0 + kk + 3];
        float2 w0 = wT2[__float_as_int(p0.y) + myo];
        float2 w1 = wT2[__float_as_int(p1.y) + myo];
        float2 w2 = wT2[__float_as_int(p2.y) + myo];
        float2 w3 = wT2[__float_as_int(p3.y) + myo];
        pA0 = fmaf(w0.x, p0.x, pA0); pC0 = fmaf(w0.x, p0.z, pC0);
        pA1 = fmaf(w0.y, p0.x, pA1); pC1 = fmaf(w0.y, p0.z, pC1);
        pA0 = fmaf(w1.x, p1.x, pA0); pC0 = fmaf(w1.x, p1.z, pC0);
        pA1 = fmaf(w1.y, p1.x, pA1); pC1 = fmaf(w1.y, p1.z, pC1);
        pA0 = fmaf(w2.x, p2.x, pA0); pC0 = fmaf(w2.x, p2.z, pC0);
        pA1 = fmaf(w2.y, p2.x, pA1); pC1 = fmaf(w2.y, p2.z, pC1);
        pA0 = fmaf(w3.x, p3.x, pA0); pC0 = fmaf(w3.x, p3.z, pC0);
        pA1 = fmaf(w3.y, p3.x, pA1); pC1 = fmaf(w3.y, p3.z, pC1);
    }
    psA[g][x] = make_float2(pA0, pA1);
    psC[g][x] = make_float2(pC0, pC1);
    __syncthreads();

    // ---- exclusive scan over g (prefix) + full totals ----
    float SA0 = 0.f, SC0 = 0.f, SA1 = 0.f, SC1 = 0.f;
    float TA0 = 0.f, TC0 = 0.f, TA1 = 0.f, TC1 = 0.f;
    for (int j = 0; j < G; ++j) {
        float2 a = psA[j][x];
        float2 c = psC[j][x];
        if (j == g) { SA0 = TA0; SC0 = TC0; SA1 = TA1; SC1 = TC1; }
        TA0 += a.x; TC0 += c.x; TA1 += a.y; TC1 += c.y;
    }

    int tcur = __float_as_int(sspk[k0].w);
    const int tend = (g == G - 1)
        ? TAIL0
        : __float_as_int(((const float*)sspk)[4 * (k0 + CH) + 3]);

    int f0 = TSTEPS, f1 = TSTEPS;

#define ADVANCE_TO(TK)                                                        \
    while (tcur < (TK)) {                                                     \
        float e = sE[tcur]; float tf = (float)tcur;                           \
        if (f0 == TSTEPS && fmaf(tf, SA0, SC0) >= e) f0 = tcur;               \
        if (f1 == TSTEPS && fmaf(tf, SA1, SC1) >= e) f1 = tcur;               \
        if (f0 != TSTEPS && f1 != TSTEPS) goto pass2_done;                    \
        ++tcur;                                                               \
    }

    // advisory skip: earlier crossings already recorded for both outputs
    if (tcur >= tend || (sFirst[2 * x] <= tcur && sFirst[2 * x + 1] <= tcur))
        goto pass2_done;

    // ---- pass 2: re-walk own chunk with threshold checks ----
#pragma unroll
    for (int kk = 0; kk < CH; kk += 4) {
        float4 p0 = sspk[k0 + kk + 0];
        float4 p1 = sspk[k0 + kk + 1];
        float4 p2 = sspk[k0 + kk + 2];
        float4 p3 = sspk[k0 + kk + 3];
        float2 w0 = wT2[__float_as_int(p0.y) + myo];
        float2 w1 = wT2[__float_as_int(p1.y) + myo];
        float2 w2 = wT2[__float_as_int(p2.y) + myo];
        float2 w3 = wT2[__float_as_int(p3.y) + myo];
        int tk;
        tk = __float_as_int(p0.w); ADVANCE_TO(tk);
        SA0 = fmaf(w0.x, p0.x, SA0); SC0 = fmaf(w0.x, p0.z, SC0);
        SA1 = fmaf(w0.y, p0.x, SA1); SC1 = fmaf(w0.y, p0.z, SC1);
        tk = __float_as_int(p1.w); ADVANCE_TO(tk);
        SA0 = fmaf(w1.x, p1.x, SA0); SC0 = fmaf(w1.x, p1.z, SC0);
        SA1 = fmaf(w1.y, p1.x, SA1); SC1 = fmaf(w1.y, p1.z, SC1);
        tk = __float_as_int(p2.w); ADVANCE_TO(tk);
        SA0 = fmaf(w2.x, p2.x, SA0); SC0 = fmaf(w2.x, p2.z, SC0);
        SA1 = fmaf(w2.y, p2.x, SA1); SC1 = fmaf(w2.y, p2.z, SC1);
        tk = __float_as_int(p3.w); ADVANCE_TO(tk);
        SA0 = fmaf(w3.x, p3.x, SA0); SC0 = fmaf(w3.x, p3.z, SC0);
        SA1 = fmaf(w3.y, p3.x, SA1); SC1 = fmaf(w3.y, p3.z, SC1);
    }
    ADVANCE_TO(tend);
#undef ADVANCE_TO

pass2_done:
    // ---- distributed spike-free tail [TAIL0, TSTEPS): 8 steps per g ----
    {
        int ts = TAIL0 + (g << 3);
        if (ts < TSTEPS) {
            bool need0 = (f0 == TSTEPS) && (sFirst[2 * x]     > ts);
            bool need1 = (f1 == TSTEPS) && (sFirst[2 * x + 1] > ts);
            if (need0 | need1) {
                int te = ts + 8 > TSTEPS ? TSTEPS : ts + 8;
                for (int t = ts; t < te; ++t) {
                    float e = sE[t]; float tf = (float)t;
                    if (need0 && fmaf(tf, TA0, TC0) >= e) { f0 = t; need0 = false; }
                    if (need1 && fmaf(tf, TA1, TC1) >= e) { f1 = t; need1 = false; }
                }
            }
        }
    }

    if (f0 < TSTEPS) atomicMin(&sFirst[2 * x], f0);
    if (f1 < TSTEPS) atomicMin(&sFirst[2 * x + 1], f1);
    __syncthreads();
    if (tid < 2 * OL)
        out[b * OUTS + blockIdx.y * (2 * OL) + tid] = (float)sFirst[tid];
}

// ---------------------------------------------------------------------------
extern "C" void kernel_launch(void* const* d_in, const int* in_sizes, int n_in,
                              void* d_out, int out_size, void* d_ws, size_t ws_size,
                              hipStream_t stream) {
    const float* in_spike = (const float*)d_in[0];   // [B, IN] fp32
    const float* weight   = (const float*)d_in[1];   // [OUT, IN] fp32
    float* out = (float*)d_out;                      // [B, OUT] fp32

    float*  wT  = (float*)d_ws;                                        // 2 MB
    float4* spk = (float4*)((char*)d_ws + (size_t)INS * OUTS * sizeof(float)); // 1 MB

    pre_kernel<<<NTRANS + BATCH, 256, 0, stream>>>(weight, wT, in_spike, spk);
    spike_scan_kernel<<<dim3(BATCH, OUTS / (2 * OL)), dim3(OL, G), 0, stream>>>(spk, wT, out);
}

// Round 6
// 95.673 us; speedup vs baseline: 2.8870x; 2.8870x over previous
//
#include <hip/hip_runtime.h>
#include <math.h>

// Problem constants: B=64, IN=1024, OUT=512, T=512, V_TH=1, TAU=16
#define BATCH   64
#define INS     1024
#define OUTS    512
#define TSTEPS  512
#define TAUF    16.0f

// ---------------------------------------------------------------------------
// Fused pre-kernel: blocks [0,128) tiled weight transpose w[OUT,IN]->wT[IN,OUT];
// blocks [128,192) per-batch spike prep + counting sort by activation time.
//   alpha(t-s) = e^{-t/tau} * (t*A + C) for t > s,
//   A = exp(1 + s/tau)/tau,  C = -s*A,  t_on = floor(s)+1 in [1,256].
// Record per spike (sorted by t_on):
//   {A, int_bits(idx*OUTS/2), C, int_bits(t_on)}
// ---------------------------------------------------------------------------
#define TT 64
#define NTRANS ((INS / TT) * (OUTS / TT))   // 128 transpose blocks

__global__ __launch_bounds__(256) void pre_kernel(
        const float* __restrict__ w, float* __restrict__ wT,
        const float* __restrict__ in_spike, float4* __restrict__ spk) {
    __shared__ float tile[TT][TT + 1];
    __shared__ int hist[257];
    __shared__ int cursor[257];
    __shared__ int scanbuf[256];

    if (blockIdx.x < NTRANS) {
        const int i0 = (blockIdx.x & (INS / TT - 1)) * TT;
        const int o0 = (blockIdx.x / (INS / TT)) * TT;
        const int c  = threadIdx.x & 63;
        const int r  = threadIdx.x >> 6;
#pragma unroll
        for (int rr = r; rr < TT; rr += 4)
            tile[rr][c] = w[(o0 + rr) * INS + i0 + c];
        __syncthreads();
#pragma unroll
        for (int rr = r; rr < TT; rr += 4)
            wT[(i0 + rr) * OUTS + o0 + c] = tile[c][rr];
        return;
    }

    const int b = blockIdx.x - NTRANS;
    for (int k = threadIdx.x; k < 257; k += 256) hist[k] = 0;
    __syncthreads();

    float sv[INS / 256];
    int   tv[INS / 256];
#pragma unroll
    for (int j = 0; j < INS / 256; ++j) {
        int i = threadIdx.x + j * 256;
        float s = in_spike[b * INS + i];
        sv[j] = s;
        int t = (int)floorf(s) + 1;
        t = t < 1 ? 1 : (t > 256 ? 256 : t);
        tv[j] = t;
        atomicAdd(&hist[t], 1);
    }
    __syncthreads();

    const int tid = threadIdx.x;
    int v = hist[tid + 1];
    scanbuf[tid] = v;
    __syncthreads();
#pragma unroll
    for (int off = 1; off < 256; off <<= 1) {
        int add = (tid >= off) ? scanbuf[tid - off] : 0;
        __syncthreads();
        scanbuf[tid] += add;
        __syncthreads();
    }
    cursor[tid + 1] = scanbuf[tid] - v;
    __syncthreads();

#pragma unroll
    for (int j = 0; j < INS / 256; ++j) {
        int i = threadIdx.x + j * 256;
        int t = tv[j];
        int pos = atomicAdd(&cursor[t], 1);
        float A = expf(fmaf(sv[j], 1.0f / TAUF, 1.0f)) * (1.0f / TAUF);
        float C = -sv[j] * A;
        spk[b * INS + pos] =
            make_float4(A, __int_as_float(i * (OUTS / 2)), C, __int_as_float(t));
    }
}

// ---------------------------------------------------------------------------
// Scan kernel (R3 skeleton + 2 outputs/thread + distributed tail).
// Block = (b, 64 outputs), 512 threads: threadIdx.x = lane (32), owning
// outputs (2x, 2x+1) via float2 gathers; threadIdx.y = time-sorted chunk g
// of 16 (64 spikes each).  Pass 1 (rolled, step 4): chunk partials.  LDS
// exclusive scan over g + totals.  Pass 2 (rolled, step 2): re-walk own
// chunk with threshold checks over the owned time range; spike-free tail
// [257,512) split 16 steps per g using totals.  Ranges partition the time
// axis -> atomicMin over per-range first crossings is exact.
//   V(t) >= 1  <=>  fma(t, SA, SC) >= exp(t/tau)   (sE table in LDS).
// Grid = 64*8 = 512 blocks; LDS 26.3 KB; plain __launch_bounds__(512).
// Wave = 32 lanes x 2 g-chunks -> 2-way LDS aliasing only (free, m136).
// ---------------------------------------------------------------------------
#define OL 32            // lanes per block (each owns 2 outputs)
#define G  16            // chunks per output
#define CH (INS / G)     // 64 spikes per chunk
#define TAIL0 257        // first spike-free time step (t_on <= 256)

__global__ __launch_bounds__(OL * G) void spike_scan_kernel(
        const float4* __restrict__ spk, const float* __restrict__ wT,
        float* __restrict__ out) {
    const int b = blockIdx.x;
    const int x = threadIdx.x;           // 0..31 lane
    const int g = threadIdx.y;           // 0..15 chunk
    const int tid = g * OL + x;

    __shared__ float4 sspk[INS];         // 16 KB
    __shared__ float  sE[TSTEPS];        // 2 KB
    __shared__ float2 psA[G][OL];        // 4 KB
    __shared__ float2 psC[G][OL];        // 4 KB
    __shared__ int    sFirst[2 * OL];    // 256 B

    const float4* bspk = spk + b * INS;
    sspk[tid]           = bspk[tid];
    sspk[tid + OL * G]  = bspk[tid + OL * G];
    if (tid < TSTEPS) sE[tid] = expf((float)tid * (1.0f / TAUF));
    if (tid < 2 * OL) sFirst[tid] = TSTEPS;
    __syncthreads();

    const int k0 = g * CH;
    const float2* __restrict__ wT2 = (const float2*)wT;
    const int myo = blockIdx.y * OL + x;          // float2 column index

    // ---- pass 1: chunk partials for outputs (2x, 2x+1); rolled step-4 ----
    float pA0 = 0.f, pC0 = 0.f, pA1 = 0.f, pC1 = 0.f;
    for (int k = k0; k < k0 + CH; k += 4) {
        float4 p0 = sspk[k + 0];
        float4 p1 = sspk[k + 1];
        float4 p2 = sspk[k + 2];
        float4 p3 = sspk[k + 3];
        float2 w0 = wT2[__float_as_int(p0.y) + myo];
        float2 w1 = wT2[__float_as_int(p1.y) + myo];
        float2 w2 = wT2[__float_as_int(p2.y) + myo];
        float2 w3 = wT2[__float_as_int(p3.y) + myo];
        pA0 = fmaf(w0.x, p0.x, pA0); pC0 = fmaf(w0.x, p0.z, pC0);
        pA1 = fmaf(w0.y, p0.x, pA1); pC1 = fmaf(w0.y, p0.z, pC1);
        pA0 = fmaf(w1.x, p1.x, pA0); pC0 = fmaf(w1.x, p1.z, pC0);
        pA1 = fmaf(w1.y, p1.x, pA1); pC1 = fmaf(w1.y, p1.z, pC1);
        pA0 = fmaf(w2.x, p2.x, pA0); pC0 = fmaf(w2.x, p2.z, pC0);
        pA1 = fmaf(w2.y, p2.x, pA1); pC1 = fmaf(w2.y, p2.z, pC1);
        pA0 = fmaf(w3.x, p3.x, pA0); pC0 = fmaf(w3.x, p3.z, pC0);
        pA1 = fmaf(w3.y, p3.x, pA1); pC1 = fmaf(w3.y, p3.z, pC1);
    }
    psA[g][x] = make_float2(pA0, pA1);
    psC[g][x] = make_float2(pC0, pC1);
    __syncthreads();

    // ---- exclusive scan over g (prefix) + full totals ----
    float SA0 = 0.f, SC0 = 0.f, SA1 = 0.f, SC1 = 0.f;
    float TA0 = 0.f, TC0 = 0.f, TA1 = 0.f, TC1 = 0.f;
    for (int j = 0; j < G; ++j) {
        float2 a = psA[j][x];
        float2 c = psC[j][x];
        if (j == g) { SA0 = TA0; SC0 = TC0; SA1 = TA1; SC1 = TC1; }
        TA0 += a.x; TC0 += c.x; TA1 += a.y; TC1 += c.y;
    }

    int tcur = __float_as_int(sspk[k0].w);
    const int tend = (g == G - 1) ? TAIL0 : __float_as_int(sspk[k0 + CH].w);

    int f0 = TSTEPS, f1 = TSTEPS;

#define ADVANCE_TO(TK)                                                        \
    while (tcur < (TK)) {                                                     \
        float e = sE[tcur]; float tf = (float)tcur;                           \
        if (f0 == TSTEPS && fmaf(tf, SA0, SC0) >= e) f0 = tcur;               \
        if (f1 == TSTEPS && fmaf(tf, SA1, SC1) >= e) f1 = tcur;               \
        if (f0 != TSTEPS && f1 != TSTEPS) goto pass2_done;                    \
        ++tcur;                                                               \
    }

    // skip pass 2 if time range empty or earlier crossings already known
    if (tcur >= tend || (sFirst[2 * x] <= tcur && sFirst[2 * x + 1] <= tcur))
        goto pass2_done;

    // ---- pass 2: rolled step-2 re-walk with threshold checks ----
    for (int k = k0; k < k0 + CH; k += 2) {
        float4 p0 = sspk[k + 0];
        float4 p1 = sspk[k + 1];
        float2 w0 = wT2[__float_as_int(p0.y) + myo];
        float2 w1 = wT2[__float_as_int(p1.y) + myo];
        int tk;
        tk = __float_as_int(p0.w); ADVANCE_TO(tk);
        SA0 = fmaf(w0.x, p0.x, SA0); SC0 = fmaf(w0.x, p0.z, SC0);
        SA1 = fmaf(w0.y, p0.x, SA1); SC1 = fmaf(w0.y, p0.z, SC1);
        tk = __float_as_int(p1.w); ADVANCE_TO(tk);
        SA0 = fmaf(w1.x, p1.x, SA0); SC0 = fmaf(w1.x, p1.z, SC0);
        SA1 = fmaf(w1.y, p1.x, SA1); SC1 = fmaf(w1.y, p1.z, SC1);
    }
    ADVANCE_TO(tend);
#undef ADVANCE_TO

pass2_done:
    // ---- distributed spike-free tail [TAIL0, TSTEPS): 16 steps per g ----
    {
        int ts = TAIL0 + (g << 4);
        if (ts < TSTEPS) {
            bool need0 = (f0 == TSTEPS) && (sFirst[2 * x]     > ts);
            bool need1 = (f1 == TSTEPS) && (sFirst[2 * x + 1] > ts);
            if (need0 | need1) {
                int te = ts + 16 > TSTEPS ? TSTEPS : ts + 16;
                for (int t = ts; t < te; ++t) {
                    float e = sE[t]; float tf = (float)t;
                    if (need0 && fmaf(tf, TA0, TC0) >= e) { f0 = t; need0 = false; }
                    if (need1 && fmaf(tf, TA1, TC1) >= e) { f1 = t; need1 = false; }
                }
            }
        }
    }

    if (f0 < TSTEPS) atomicMin(&sFirst[2 * x], f0);
    if (f1 < TSTEPS) atomicMin(&sFirst[2 * x + 1], f1);
    __syncthreads();
    if (tid < 2 * OL)
        out[b * OUTS + blockIdx.y * (2 * OL) + tid] = (float)sFirst[tid];
}

// ---------------------------------------------------------------------------
extern "C" void kernel_launch(void* const* d_in, const int* in_sizes, int n_in,
                              void* d_out, int out_size, void* d_ws, size_t ws_size,
                              hipStream_t stream) {
    const float* in_spike = (const float*)d_in[0];   // [B, IN] fp32
    const float* weight   = (const float*)d_in[1];   // [OUT, IN] fp32
    float* out = (float*)d_out;                      // [B, OUT] fp32

    float*  wT  = (float*)d_ws;                                        // 2 MB
    float4* spk = (float4*)((char*)d_ws + (size_t)INS * OUTS * sizeof(float)); // 1 MB

    pre_kernel<<<NTRANS + BATCH, 256, 0, stream>>>(weight, wT, in_spike, spk);
    spike_scan_kernel<<<dim3(BATCH, OUTS / (2 * OL)), dim3(OL, G), 0, stream>>>(spk, wT, out);
}